// Round 2
// baseline (347.119 us; speedup 1.0000x reference)
//
#include <hip/hip_runtime.h>
#include <math.h>

typedef __attribute__((ext_vector_type(8))) short s8vec;
typedef __attribute__((ext_vector_type(8))) __bf16 bf8vec;
typedef __attribute__((ext_vector_type(4))) float f4vec;

__device__ __forceinline__ unsigned short f2bf(float f) {
  unsigned u = __float_as_uint(f);
  u += 0x7fffu + ((u >> 16) & 1u);  // RNE (finite values only)
  return (unsigned short)(u >> 16);
}

__device__ __forceinline__ f4vec MFMA(s8vec a, s8vec b, f4vec c) {
  return __builtin_amdgcn_mfma_f32_16x16x32_bf16(
      __builtin_bit_cast(bf8vec, a), __builtin_bit_cast(bf8vec, b), c, 0, 0, 0);
}

// B=32, H=W=64, C=128, S=8, NH=4, HD=32; windows = 2048, tokens = 131072.

// ---------- K0: weight fp32 -> bf16 (qkv | proj | fc1 | fc2 concatenated) ----------
__global__ __launch_bounds__(256) void wconv_k(
    const float* __restrict__ qkvw, const float* __restrict__ projw,
    const float* __restrict__ f1w, const float* __restrict__ f2w,
    short* __restrict__ out) {
  int i = blockIdx.x * 256 + threadIdx.x;  // grid covers 196608 exactly
  float v;
  if (i < 49152)        v = qkvw[i];
  else if (i < 65536)   v = projw[i - 49152];
  else if (i < 131072)  v = f1w[i - 65536];
  else                  v = f2w[i - 131072];
  out[i] = (short)f2bf(v);
}

// ---------- K1: fused MSA: LN1+gather -> QKV -> attention -> proj+residual ----------
// 1 block = 1 window (64 tokens), 4 waves, wave h = head h. LDS 64 KB -> 2 blk/CU.
__global__ __launch_bounds__(256) void msa_k(
    const float* __restrict__ x, const float* __restrict__ ln1w,
    const float* __restrict__ ln1b, const short* __restrict__ wq,
    const float* __restrict__ qkvb, const short* __restrict__ wp,
    const float* __restrict__ projb, float* __restrict__ out) {
  __shared__ short xs[8192];   // [64][128] swz: LN1 out; later attn-out (aliased)
  __shared__ short qk[16384];  // q[64][128]@0, k[64][128]@8192; later P[h]@h*4096
  __shared__ short vt[8192];   // vT [128][64] swz (rows h*32.. per head)

  const int wi = blockIdx.x, tid = threadIdx.x;
  const int bb = wi >> 6, hy = (wi >> 3) & 7, wx = wi & 7;
  const f4vec fz = {0.f, 0.f, 0.f, 0.f};

  // ---- phase A: LN1 with roll+window gather (4 lanes per token) ----
  {
    const int t = tid >> 2, sub = tid & 3;
    const int sy = t >> 3, sx = t & 7;
    const int py = (sy * 8 + hy + 8) & 63, px = (sx * 8 + wx + 8) & 63;
    const float* xr = x + ((size_t)(bb * 4096 + py * 64 + px)) * 128 + sub * 32;
    float vv[32];
    float s = 0.f, sq = 0.f;
#pragma unroll
    for (int j = 0; j < 8; ++j) {
      float4 f = ((const float4*)xr)[j];
      vv[j * 4 + 0] = f.x; vv[j * 4 + 1] = f.y;
      vv[j * 4 + 2] = f.z; vv[j * 4 + 3] = f.w;
      s += f.x + f.y + f.z + f.w;
      sq += f.x * f.x + f.y * f.y + f.z * f.z + f.w * f.w;
    }
    s += __shfl_xor(s, 1);  s += __shfl_xor(s, 2);
    sq += __shfl_xor(sq, 1); sq += __shfl_xor(sq, 2);
    const float mean = s * 0.0078125f;
    const float rs = rsqrtf(sq * 0.0078125f - mean * mean + 1e-5f);
#pragma unroll
    for (int j8 = 0; j8 < 4; ++j8) {
      s8vec p;
#pragma unroll
      for (int e = 0; e < 8; ++e) {
        int c = sub * 32 + j8 * 8 + e;
        p[e] = (short)f2bf((vv[j8 * 8 + e] - mean) * rs * ln1w[c] + ln1b[c]);
      }
      *(s8vec*)(xs + t * 128 + (((sub * 4 + j8) ^ (t & 7)) << 3)) = p;
    }
  }
  __syncthreads();  // #1: xs ready

  const int h = tid >> 6, lane = tid & 63, g = lane >> 4, li = lane & 15;
  const int sl = li & 7;

  // ---- phase B: QKV for own head (64 x 96), W frags straight from L2 ----
  f4vec acc[4][6];
#pragma unroll
  for (int mi = 0; mi < 4; ++mi)
#pragma unroll
    for (int ng = 0; ng < 6; ++ng) acc[mi][ng] = fz;
#pragma unroll
  for (int kk = 0; kk < 4; ++kk) {
    s8vec a0[4];
#pragma unroll
    for (int mi = 0; mi < 4; ++mi)
      a0[mi] = *(const s8vec*)(xs + (mi * 16 + li) * 128 + (((kk * 4 + g) ^ sl) << 3));
#pragma unroll
    for (int ng = 0; ng < 6; ++ng) {
      s8vec bw = *(const s8vec*)(wq + (size_t)(h * 96 + ng * 16 + li) * 128 + kk * 32 + g * 8);
#pragma unroll
      for (int mi = 0; mi < 4; ++mi) acc[mi][ng] = MFMA(a0[mi], bw, acc[mi][ng]);
    }
  }
  // scatter q/k/vT to LDS (own-wave regions; same-wave LDS is in-order)
#pragma unroll
  for (int ng = 0; ng < 6; ++ng) {
    const int tt = ng >> 1;                 // 0=q 1=k 2=v (compile-time)
    const int hd = (ng & 1) * 16 + li;      // 0..31
    const float bias = qkvb[h * 96 + ng * 16 + li];
#pragma unroll
    for (int mi = 0; mi < 4; ++mi)
#pragma unroll
      for (int r = 0; r < 4; ++r) {
        int i = mi * 16 + g * 4 + r;
        short bv = (short)f2bf(acc[mi][ng][r] + bias);
        if (tt == 0)
          qk[i * 128 + (((h * 4 + (hd >> 3)) ^ (i & 7)) << 3) + (hd & 7)] = bv;
        else if (tt == 1)
          qk[8192 + i * 128 + (((h * 4 + (hd >> 3)) ^ (i & 7)) << 3) + (hd & 7)] = bv;
        else
          vt[(h * 32 + hd) * 64 + (((i >> 3) ^ (hd & 7)) << 3) + (i & 7)] = bv;
      }
  }

  // load q,k fragments BEFORE P overlays q/k region
  s8vec qf[4], kf[4];
#pragma unroll
  for (int mi = 0; mi < 4; ++mi)
    qf[mi] = *(const s8vec*)(qk + (mi * 16 + li) * 128 + (((h * 4 + g) ^ sl) << 3));
#pragma unroll
  for (int ni = 0; ni < 4; ++ni)
    kf[ni] = *(const s8vec*)(qk + 8192 + (ni * 16 + li) * 128 + (((h * 4 + g) ^ sl) << 3));
  __syncthreads();  // #2: all q/k/xs reads done; P and aout overlays now safe

  // ---- phase C: QK^T, softmax, PV ----
  f4vec e[4][4];
#pragma unroll
  for (int mi = 0; mi < 4; ++mi)
#pragma unroll
    for (int ni = 0; ni < 4; ++ni) e[mi][ni] = fz;
#pragma unroll
  for (int mi = 0; mi < 4; ++mi)
#pragma unroll
    for (int ni = 0; ni < 4; ++ni) e[mi][ni] = MFMA(qf[mi], kf[ni], e[mi][ni]);

  const float scale = 0.17677669529663687f;  // 1/sqrt(32); "+1.0" cancels in softmax
  short* Pm = qk + h * 4096;                 // 64x64 bf16, swizzled
#pragma unroll
  for (int mi = 0; mi < 4; ++mi)
#pragma unroll
    for (int r = 0; r < 4; ++r) {
      float mx = e[mi][0][r];
#pragma unroll
      for (int ni = 1; ni < 4; ++ni) mx = fmaxf(mx, e[mi][ni][r]);
#pragma unroll
      for (int m = 1; m < 16; m <<= 1) mx = fmaxf(mx, __shfl_xor(mx, m));
      float pr[4], sm = 0.f;
#pragma unroll
      for (int ni = 0; ni < 4; ++ni) {
        pr[ni] = __expf((e[mi][ni][r] - mx) * scale);
        sm += pr[ni];
      }
#pragma unroll
      for (int m = 1; m < 16; m <<= 1) sm += __shfl_xor(sm, m);
      float inv = 1.0f / sm;
      int i = mi * 16 + g * 4 + r;
#pragma unroll
      for (int ni = 0; ni < 4; ++ni) {
        int j = ni * 16 + li;
        Pm[i * 64 + (((j >> 3) ^ (i & 7)) << 3) + (j & 7)] = (short)f2bf(pr[ni] * inv);
      }
    }

  s8vec vf[2][2];
#pragma unroll
  for (int di = 0; di < 2; ++di)
#pragma unroll
    for (int kk = 0; kk < 2; ++kk)
      vf[di][kk] = *(const s8vec*)(vt + (h * 32 + di * 16 + li) * 64 + (((kk * 4 + g) ^ sl) << 3));

  f4vec o[4][2];
#pragma unroll
  for (int mi = 0; mi < 4; ++mi)
#pragma unroll
    for (int di = 0; di < 2; ++di) o[mi][di] = fz;
#pragma unroll
  for (int kk = 0; kk < 2; ++kk)
#pragma unroll
    for (int mi = 0; mi < 4; ++mi) {
      s8vec pa = *(const s8vec*)(Pm + (mi * 16 + li) * 64 + (((kk * 4 + g) ^ sl) << 3));
#pragma unroll
      for (int di = 0; di < 2; ++di) o[mi][di] = MFMA(pa, vf[di][kk], o[mi][di]);
    }

  // attn-out -> xs (overlay; all xs/LN reads finished before barrier #2)
#pragma unroll
  for (int mi = 0; mi < 4; ++mi)
#pragma unroll
    for (int di = 0; di < 2; ++di)
#pragma unroll
      for (int r = 0; r < 4; ++r) {
        int i = mi * 16 + g * 4 + r;
        int c8 = h * 4 + di * 2 + (li >> 3);
        xs[i * 128 + ((c8 ^ (i & 7)) << 3) + sl] = (short)f2bf(o[mi][di][r]);
      }
  __syncthreads();  // #3: attn-out visible to all waves

  // ---- phase D: proj + bias + un-permute + residual -> out (fp32) ----
  f4vec pacc[4][2];
#pragma unroll
  for (int mi = 0; mi < 4; ++mi)
#pragma unroll
    for (int nj = 0; nj < 2; ++nj) pacc[mi][nj] = fz;
#pragma unroll
  for (int kk = 0; kk < 4; ++kk) {
    s8vec a0[4];
#pragma unroll
    for (int mi = 0; mi < 4; ++mi)
      a0[mi] = *(const s8vec*)(xs + (mi * 16 + li) * 128 + (((kk * 4 + g) ^ sl) << 3));
#pragma unroll
    for (int nj = 0; nj < 2; ++nj) {
      s8vec bw = *(const s8vec*)(wp + (size_t)(h * 32 + nj * 16 + li) * 128 + kk * 32 + g * 8);
#pragma unroll
      for (int mi = 0; mi < 4; ++mi) pacc[mi][nj] = MFMA(a0[mi], bw, pacc[mi][nj]);
    }
  }
#pragma unroll
  for (int nj = 0; nj < 2; ++nj) {
    const int col = h * 32 + nj * 16 + li;
    const float bias = projb[col];
#pragma unroll
    for (int mi = 0; mi < 4; ++mi)
#pragma unroll
      for (int r = 0; r < 4; ++r) {
        int i = mi * 16 + g * 4 + r;
        int sy = i >> 3, sx = i & 7;
        int py = (sy * 8 + hy + 8) & 63, px = (sx * 8 + wx + 8) & 63;
        size_t dst = ((size_t)(bb * 4096 + py * 64 + px)) * 128 + col;
        out[dst] = x[dst] + pacc[mi][nj][r] + bias;
      }
  }
}

// ---------- K2: fused MLP: LN2 -> FC1+GELU (hid in LDS) -> FC2+residual ----------
// 1 block = 64 rows, 4 waves (wave w: FC1 cols 128w.., FC2 cols 32w..). LDS 80 KB.
__global__ __launch_bounds__(256) void mlp_k(
    const float* __restrict__ ln2w, const float* __restrict__ ln2b,
    const short* __restrict__ w1, const float* __restrict__ fc1b,
    const short* __restrict__ w2, const float* __restrict__ fc2b,
    float* __restrict__ io) {
  __shared__ short ls[8192];    // [64][128] LN2 out, swz
  __shared__ short hs[32768];   // [64][512] hid bf16, swz
  const int tid = threadIdx.x;
  const size_t rbase = (size_t)blockIdx.x * 64;
  const f4vec fz = {0.f, 0.f, 0.f, 0.f};

  {  // LN2 (reads msa from io; io is fully rewritten by msa_k every call)
    const int t = tid >> 2, sub = tid & 3;
    const float* xr = io + (rbase + t) * 128 + sub * 32;
    float vv[32];
    float s = 0.f, sq = 0.f;
#pragma unroll
    for (int j = 0; j < 8; ++j) {
      float4 f = ((const float4*)xr)[j];
      vv[j * 4 + 0] = f.x; vv[j * 4 + 1] = f.y;
      vv[j * 4 + 2] = f.z; vv[j * 4 + 3] = f.w;
      s += f.x + f.y + f.z + f.w;
      sq += f.x * f.x + f.y * f.y + f.z * f.z + f.w * f.w;
    }
    s += __shfl_xor(s, 1);  s += __shfl_xor(s, 2);
    sq += __shfl_xor(sq, 1); sq += __shfl_xor(sq, 2);
    const float mean = s * 0.0078125f;
    const float rs = rsqrtf(sq * 0.0078125f - mean * mean + 1e-5f);
#pragma unroll
    for (int j8 = 0; j8 < 4; ++j8) {
      s8vec p;
#pragma unroll
      for (int e = 0; e < 8; ++e) {
        int c = sub * 32 + j8 * 8 + e;
        p[e] = (short)f2bf((vv[j8 * 8 + e] - mean) * rs * ln2w[c] + ln2b[c]);
      }
      *(s8vec*)(ls + t * 128 + (((sub * 4 + j8) ^ (t & 7)) << 3)) = p;
    }
  }
  __syncthreads();

  const int w = tid >> 6, lane = tid & 63, g = lane >> 4, li = lane & 15;
  const int sl = li & 7;

  // ---- FC1 + GELU -> hs ----
  {
    f4vec acc[4][8];
#pragma unroll
    for (int mi = 0; mi < 4; ++mi)
#pragma unroll
      for (int ni = 0; ni < 8; ++ni) acc[mi][ni] = fz;
#pragma unroll
    for (int kk = 0; kk < 4; ++kk) {
      s8vec a0[4];
#pragma unroll
      for (int mi = 0; mi < 4; ++mi)
        a0[mi] = *(const s8vec*)(ls + (mi * 16 + li) * 128 + (((kk * 4 + g) ^ sl) << 3));
#pragma unroll
      for (int ni = 0; ni < 8; ++ni) {
        s8vec bw = *(const s8vec*)(w1 + (size_t)(w * 128 + ni * 16 + li) * 128 + kk * 32 + g * 8);
#pragma unroll
        for (int mi = 0; mi < 4; ++mi) acc[mi][ni] = MFMA(a0[mi], bw, acc[mi][ni]);
      }
    }
#pragma unroll
    for (int ni = 0; ni < 8; ++ni) {
      const float bias = fc1b[w * 128 + ni * 16 + li];
      const int c8 = w * 16 + ni * 2 + (li >> 3);
#pragma unroll
      for (int mi = 0; mi < 4; ++mi)
#pragma unroll
        for (int r = 0; r < 4; ++r) {
          int i = mi * 16 + g * 4 + r;
          float v = acc[mi][ni][r] + bias;
          float ge = 0.5f * v * (1.f + erff(v * 0.70710678118f));
          hs[i * 512 + ((c8 ^ (i & 7)) << 3) + sl] = (short)f2bf(ge);
        }
    }
  }
  __syncthreads();

  // ---- FC2 + bias + residual (in-place on io; col ranges disjoint per wave) ----
  f4vec acc2[4][2];
#pragma unroll
  for (int mi = 0; mi < 4; ++mi)
#pragma unroll
    for (int nj = 0; nj < 2; ++nj) acc2[mi][nj] = fz;
#pragma unroll
  for (int kk = 0; kk < 16; ++kk) {
    s8vec a0[4];
#pragma unroll
    for (int mi = 0; mi < 4; ++mi)
      a0[mi] = *(const s8vec*)(hs + (mi * 16 + li) * 512 + (((kk * 4 + g) ^ sl) << 3));
#pragma unroll
    for (int nj = 0; nj < 2; ++nj) {
      s8vec bw = *(const s8vec*)(w2 + (size_t)(w * 32 + nj * 16 + li) * 512 + kk * 32 + g * 8);
#pragma unroll
      for (int mi = 0; mi < 4; ++mi) acc2[mi][nj] = MFMA(a0[mi], bw, acc2[mi][nj]);
    }
  }
#pragma unroll
  for (int nj = 0; nj < 2; ++nj) {
    const int col = w * 32 + nj * 16 + li;
    const float bias = fc2b[col];
#pragma unroll
    for (int mi = 0; mi < 4; ++mi)
#pragma unroll
      for (int r = 0; r < 4; ++r) {
        int i = mi * 16 + g * 4 + r;
        size_t dst = (rbase + i) * 128 + col;
        io[dst] = io[dst] + acc2[mi][nj][r] + bias;
      }
  }
}

// ---------- launch ----------
extern "C" void kernel_launch(void* const* d_in, const int* in_sizes, int n_in,
                              void* d_out, int out_size, void* d_ws, size_t ws_size,
                              hipStream_t stream) {
  const float* x     = (const float*)d_in[0];
  const float* ln1w  = (const float*)d_in[1];
  const float* ln1b  = (const float*)d_in[2];
  const float* qkvw  = (const float*)d_in[3];
  const float* qkvb  = (const float*)d_in[4];
  const float* projw = (const float*)d_in[5];
  const float* projb = (const float*)d_in[6];
  const float* ln2w  = (const float*)d_in[7];
  const float* ln2b  = (const float*)d_in[8];
  const float* fc1w  = (const float*)d_in[9];
  const float* fc1b  = (const float*)d_in[10];
  const float* fc2w  = (const float*)d_in[11];
  const float* fc2b  = (const float*)d_in[12];

  short* wb = (short*)d_ws;  // bf16 weights: qkv@0, proj@49152, fc1@65536, fc2@131072
  float* out = (float*)d_out;

  wconv_k<<<768, 256, 0, stream>>>(qkvw, projw, fc1w, fc2w, wb);
  msa_k<<<2048, 256, 0, stream>>>(x, ln1w, ln1b, wb, qkvb, wb + 49152, projb, out);
  mlp_k<<<2048, 256, 0, stream>>>(ln2w, ln2b, wb + 65536, fc1b, wb + 131072, fc2b, out);
}

// Round 3
// 288.545 us; speedup vs baseline: 1.2030x; 1.2030x over previous
//
#include <hip/hip_runtime.h>
#include <math.h>

typedef __attribute__((ext_vector_type(8))) short s8vec;
typedef __attribute__((ext_vector_type(8))) __bf16 bf8vec;
typedef __attribute__((ext_vector_type(4))) float f4vec;

__device__ __forceinline__ unsigned short f2bf(float f) {
  unsigned u = __float_as_uint(f);
  u += 0x7fffu + ((u >> 16) & 1u);  // RNE (finite values only)
  return (unsigned short)(u >> 16);
}

__device__ __forceinline__ f4vec MFMA(s8vec a, s8vec b, f4vec c) {
  return __builtin_amdgcn_mfma_f32_16x16x32_bf16(
      __builtin_bit_cast(bf8vec, a), __builtin_bit_cast(bf8vec, b), c, 0, 0, 0);
}

// B=32, H=W=64, C=128, S=8, NH=4, HD=32; windows = 2048, tokens = 131072.

// ---------- K0: weight fp32 -> bf16 (qkv | proj | fc1 | fc2 concatenated) ----------
__global__ __launch_bounds__(256) void wconv_k(
    const float* __restrict__ qkvw, const float* __restrict__ projw,
    const float* __restrict__ f1w, const float* __restrict__ f2w,
    short* __restrict__ out) {
  int i = blockIdx.x * 256 + threadIdx.x;  // grid covers 196608 exactly
  float v;
  if (i < 49152)        v = qkvw[i];
  else if (i < 65536)   v = projw[i - 49152];
  else if (i < 131072)  v = f1w[i - 65536];
  else                  v = f2w[i - 131072];
  out[i] = (short)f2bf(v);
}

// ---------- K1: fused MSA: LN1+gather -> QKV -> attention -> proj+residual ----------
// 1 block = 1 window (64 tokens), 4 waves, wave h = head h. LDS 64 KB -> 2 blk/CU.
__global__ __launch_bounds__(256) void msa_k(
    const float* __restrict__ x, const float* __restrict__ ln1w,
    const float* __restrict__ ln1b, const short* __restrict__ wq,
    const float* __restrict__ qkvb, const short* __restrict__ wp,
    const float* __restrict__ projb, float* __restrict__ out) {
  __shared__ short xs[8192];   // [64][128] swz: LN1 out; later attn-out (aliased)
  __shared__ short qk[16384];  // q[64][128]@0, k[64][128]@8192; later P[h]@h*4096
  __shared__ short vt[8192];   // vT [128][64] swz (rows h*32.. per head)

  const int wi = blockIdx.x, tid = threadIdx.x;
  const int bb = wi >> 6, hy = (wi >> 3) & 7, wx = wi & 7;
  const f4vec fz = {0.f, 0.f, 0.f, 0.f};

  // ---- phase A: LN1 with roll+window gather (4 lanes per token) ----
  {
    const int t = tid >> 2, sub = tid & 3;
    const int sy = t >> 3, sx = t & 7;
    const int py = (sy * 8 + hy + 8) & 63, px = (sx * 8 + wx + 8) & 63;
    const float* xr = x + ((size_t)(bb * 4096 + py * 64 + px)) * 128 + sub * 32;
    float vv[32];
    float s = 0.f, sq = 0.f;
#pragma unroll
    for (int j = 0; j < 8; ++j) {
      float4 f = ((const float4*)xr)[j];
      vv[j * 4 + 0] = f.x; vv[j * 4 + 1] = f.y;
      vv[j * 4 + 2] = f.z; vv[j * 4 + 3] = f.w;
      s += f.x + f.y + f.z + f.w;
      sq += f.x * f.x + f.y * f.y + f.z * f.z + f.w * f.w;
    }
    s += __shfl_xor(s, 1);  s += __shfl_xor(s, 2);
    sq += __shfl_xor(sq, 1); sq += __shfl_xor(sq, 2);
    const float mean = s * 0.0078125f;
    const float rs = rsqrtf(sq * 0.0078125f - mean * mean + 1e-5f);
#pragma unroll
    for (int j8 = 0; j8 < 4; ++j8) {
      s8vec p;
#pragma unroll
      for (int e = 0; e < 8; ++e) {
        int c = sub * 32 + j8 * 8 + e;
        p[e] = (short)f2bf((vv[j8 * 8 + e] - mean) * rs * ln1w[c] + ln1b[c]);
      }
      *(s8vec*)(xs + t * 128 + (((sub * 4 + j8) ^ (t & 7)) << 3)) = p;
    }
  }
  __syncthreads();  // #1: xs ready

  const int h = tid >> 6, lane = tid & 63, g = lane >> 4, li = lane & 15;
  const int sl = li & 7;

  // ---- phase B: QKV for own head (64 x 96), W frags straight from L2 ----
  f4vec acc[4][6];
#pragma unroll
  for (int mi = 0; mi < 4; ++mi)
#pragma unroll
    for (int ng = 0; ng < 6; ++ng) acc[mi][ng] = fz;
#pragma unroll
  for (int kk = 0; kk < 4; ++kk) {
    s8vec a0[4];
#pragma unroll
    for (int mi = 0; mi < 4; ++mi)
      a0[mi] = *(const s8vec*)(xs + (mi * 16 + li) * 128 + (((kk * 4 + g) ^ sl) << 3));
#pragma unroll
    for (int ng = 0; ng < 6; ++ng) {
      s8vec bw = *(const s8vec*)(wq + (size_t)(h * 96 + ng * 16 + li) * 128 + kk * 32 + g * 8);
#pragma unroll
      for (int mi = 0; mi < 4; ++mi) acc[mi][ng] = MFMA(a0[mi], bw, acc[mi][ng]);
    }
  }
  // scatter q/k/vT to LDS (own-wave regions; same-wave LDS is in-order)
#pragma unroll
  for (int ng = 0; ng < 6; ++ng) {
    const int tt = ng >> 1;                 // 0=q 1=k 2=v (compile-time)
    const int hd = (ng & 1) * 16 + li;      // 0..31
    const float bias = qkvb[h * 96 + ng * 16 + li];
#pragma unroll
    for (int mi = 0; mi < 4; ++mi)
#pragma unroll
      for (int r = 0; r < 4; ++r) {
        int i = mi * 16 + g * 4 + r;
        short bv = (short)f2bf(acc[mi][ng][r] + bias);
        if (tt == 0)
          qk[i * 128 + (((h * 4 + (hd >> 3)) ^ (i & 7)) << 3) + (hd & 7)] = bv;
        else if (tt == 1)
          qk[8192 + i * 128 + (((h * 4 + (hd >> 3)) ^ (i & 7)) << 3) + (hd & 7)] = bv;
        else
          vt[(h * 32 + hd) * 64 + (((i >> 3) ^ (hd & 7)) << 3) + (i & 7)] = bv;
      }
  }

  // load q,k fragments BEFORE P overlays q/k region
  s8vec qf[4], kf[4];
#pragma unroll
  for (int mi = 0; mi < 4; ++mi)
    qf[mi] = *(const s8vec*)(qk + (mi * 16 + li) * 128 + (((h * 4 + g) ^ sl) << 3));
#pragma unroll
  for (int ni = 0; ni < 4; ++ni)
    kf[ni] = *(const s8vec*)(qk + 8192 + (ni * 16 + li) * 128 + (((h * 4 + g) ^ sl) << 3));
  __syncthreads();  // #2: all q/k/xs reads done; P and aout overlays now safe

  // ---- phase C: QK^T, softmax, PV ----
  f4vec e[4][4];
#pragma unroll
  for (int mi = 0; mi < 4; ++mi)
#pragma unroll
    for (int ni = 0; ni < 4; ++ni) e[mi][ni] = fz;
#pragma unroll
  for (int mi = 0; mi < 4; ++mi)
#pragma unroll
    for (int ni = 0; ni < 4; ++ni) e[mi][ni] = MFMA(qf[mi], kf[ni], e[mi][ni]);

  const float scale = 0.17677669529663687f;  // 1/sqrt(32); "+1.0" cancels in softmax
  short* Pm = qk + h * 4096;                 // 64x64 bf16, swizzled
#pragma unroll
  for (int mi = 0; mi < 4; ++mi)
#pragma unroll
    for (int r = 0; r < 4; ++r) {
      float mx = e[mi][0][r];
#pragma unroll
      for (int ni = 1; ni < 4; ++ni) mx = fmaxf(mx, e[mi][ni][r]);
#pragma unroll
      for (int m = 1; m < 16; m <<= 1) mx = fmaxf(mx, __shfl_xor(mx, m));
      float pr[4], sm = 0.f;
#pragma unroll
      for (int ni = 0; ni < 4; ++ni) {
        pr[ni] = __expf((e[mi][ni][r] - mx) * scale);
        sm += pr[ni];
      }
#pragma unroll
      for (int m = 1; m < 16; m <<= 1) sm += __shfl_xor(sm, m);
      float inv = 1.0f / sm;
      int i = mi * 16 + g * 4 + r;
#pragma unroll
      for (int ni = 0; ni < 4; ++ni) {
        int j = ni * 16 + li;
        Pm[i * 64 + (((j >> 3) ^ (i & 7)) << 3) + (j & 7)] = (short)f2bf(pr[ni] * inv);
      }
    }

  s8vec vf[2][2];
#pragma unroll
  for (int di = 0; di < 2; ++di)
#pragma unroll
    for (int kk = 0; kk < 2; ++kk)
      vf[di][kk] = *(const s8vec*)(vt + (h * 32 + di * 16 + li) * 64 + (((kk * 4 + g) ^ sl) << 3));

  f4vec o[4][2];
#pragma unroll
  for (int mi = 0; mi < 4; ++mi)
#pragma unroll
    for (int di = 0; di < 2; ++di) o[mi][di] = fz;
#pragma unroll
  for (int kk = 0; kk < 2; ++kk)
#pragma unroll
    for (int mi = 0; mi < 4; ++mi) {
      s8vec pa = *(const s8vec*)(Pm + (mi * 16 + li) * 64 + (((kk * 4 + g) ^ sl) << 3));
#pragma unroll
      for (int di = 0; di < 2; ++di) o[mi][di] = MFMA(pa, vf[di][kk], o[mi][di]);
    }

  // attn-out -> xs (overlay; all xs/LN reads finished before barrier #2)
#pragma unroll
  for (int mi = 0; mi < 4; ++mi)
#pragma unroll
    for (int di = 0; di < 2; ++di)
#pragma unroll
      for (int r = 0; r < 4; ++r) {
        int i = mi * 16 + g * 4 + r;
        int c8 = h * 4 + di * 2 + (li >> 3);
        xs[i * 128 + ((c8 ^ (i & 7)) << 3) + sl] = (short)f2bf(o[mi][di][r]);
      }
  __syncthreads();  // #3: attn-out visible to all waves

  // ---- phase D: proj + bias + un-permute + residual -> out (fp32) ----
  f4vec pacc[4][2];
#pragma unroll
  for (int mi = 0; mi < 4; ++mi)
#pragma unroll
    for (int nj = 0; nj < 2; ++nj) pacc[mi][nj] = fz;
#pragma unroll
  for (int kk = 0; kk < 4; ++kk) {
    s8vec a0[4];
#pragma unroll
    for (int mi = 0; mi < 4; ++mi)
      a0[mi] = *(const s8vec*)(xs + (mi * 16 + li) * 128 + (((kk * 4 + g) ^ sl) << 3));
#pragma unroll
    for (int nj = 0; nj < 2; ++nj) {
      s8vec bw = *(const s8vec*)(wp + (size_t)(h * 32 + nj * 16 + li) * 128 + kk * 32 + g * 8);
#pragma unroll
      for (int mi = 0; mi < 4; ++mi) pacc[mi][nj] = MFMA(a0[mi], bw, pacc[mi][nj]);
    }
  }
#pragma unroll
  for (int nj = 0; nj < 2; ++nj) {
    const int col = h * 32 + nj * 16 + li;
    const float bias = projb[col];
#pragma unroll
    for (int mi = 0; mi < 4; ++mi)
#pragma unroll
      for (int r = 0; r < 4; ++r) {
        int i = mi * 16 + g * 4 + r;
        int sy = i >> 3, sx = i & 7;
        int py = (sy * 8 + hy + 8) & 63, px = (sx * 8 + wx + 8) & 63;
        size_t dst = ((size_t)(bb * 4096 + py * 64 + px)) * 128 + col;
        out[dst] = x[dst] + pacc[mi][nj][r] + bias;
      }
  }
}

// ---------- K2: fused MLP: LN2 -> FC1+GELU (hid in LDS) -> FC2+residual ----------
// 1 block = 32 rows, 4 waves (wave w: FC1 cols 128w.., FC2 cols 32w..).
// LDS 40 KB -> 4 blk/CU; __launch_bounds__(256,4) caps VGPR at 128 -> 16 waves/CU.
__global__ __launch_bounds__(256, 4) void mlp_k(
    const float* __restrict__ ln2w, const float* __restrict__ ln2b,
    const short* __restrict__ w1, const float* __restrict__ fc1b,
    const short* __restrict__ w2, const float* __restrict__ fc2b,
    float* __restrict__ io) {
  __shared__ short ls[4096];    // [32][128] LN2 out, swz
  __shared__ short hs[16384];   // [32][512] hid bf16, swz
  const int tid = threadIdx.x;
  const size_t rbase = (size_t)blockIdx.x * 32;
  const f4vec fz = {0.f, 0.f, 0.f, 0.f};

  {  // LN2: 8 lanes per row, 16 floats each (io fully rewritten by msa_k every call)
    const int t = tid >> 3, sub = tid & 7;
    const float* xr = io + (rbase + t) * 128 + sub * 16;
    float vv[16];
    float s = 0.f, sq = 0.f;
#pragma unroll
    for (int j = 0; j < 4; ++j) {
      float4 f = ((const float4*)xr)[j];
      vv[j * 4 + 0] = f.x; vv[j * 4 + 1] = f.y;
      vv[j * 4 + 2] = f.z; vv[j * 4 + 3] = f.w;
      s += f.x + f.y + f.z + f.w;
      sq += f.x * f.x + f.y * f.y + f.z * f.z + f.w * f.w;
    }
    s += __shfl_xor(s, 1);  s += __shfl_xor(s, 2);  s += __shfl_xor(s, 4);
    sq += __shfl_xor(sq, 1); sq += __shfl_xor(sq, 2); sq += __shfl_xor(sq, 4);
    const float mean = s * 0.0078125f;
    const float rs = rsqrtf(sq * 0.0078125f - mean * mean + 1e-5f);
#pragma unroll
    for (int j8 = 0; j8 < 2; ++j8) {
      s8vec p;
#pragma unroll
      for (int e = 0; e < 8; ++e) {
        int c = sub * 16 + j8 * 8 + e;
        p[e] = (short)f2bf((vv[j8 * 8 + e] - mean) * rs * ln2w[c] + ln2b[c]);
      }
      *(s8vec*)(ls + t * 128 + (((sub * 2 + j8) ^ (t & 7)) << 3)) = p;
    }
  }
  __syncthreads();

  const int w = tid >> 6, lane = tid & 63, g = lane >> 4, li = lane & 15;
  const int sl = li & 7;

  // ---- FC1 + GELU -> hs (wave w: hid cols 128w..128w+127) ----
  {
    f4vec acc[2][8];
#pragma unroll
    for (int mi = 0; mi < 2; ++mi)
#pragma unroll
      for (int ni = 0; ni < 8; ++ni) acc[mi][ni] = fz;
#pragma unroll
    for (int kk = 0; kk < 4; ++kk) {
      s8vec a0[2];
#pragma unroll
      for (int mi = 0; mi < 2; ++mi)
        a0[mi] = *(const s8vec*)(ls + (mi * 16 + li) * 128 + (((kk * 4 + g) ^ sl) << 3));
#pragma unroll
      for (int ni = 0; ni < 8; ++ni) {
        s8vec bw = *(const s8vec*)(w1 + (size_t)(w * 128 + ni * 16 + li) * 128 + kk * 32 + g * 8);
#pragma unroll
        for (int mi = 0; mi < 2; ++mi) acc[mi][ni] = MFMA(a0[mi], bw, acc[mi][ni]);
      }
    }
#pragma unroll
    for (int ni = 0; ni < 8; ++ni) {
      const float bias = fc1b[w * 128 + ni * 16 + li];
      const int c8 = w * 16 + ni * 2 + (li >> 3);
#pragma unroll
      for (int mi = 0; mi < 2; ++mi)
#pragma unroll
        for (int r = 0; r < 4; ++r) {
          int i = mi * 16 + g * 4 + r;
          float v = acc[mi][ni][r] + bias;
          float ge = 0.5f * v * (1.f + erff(v * 0.70710678118f));
          hs[i * 512 + ((c8 ^ (i & 7)) << 3) + sl] = (short)f2bf(ge);
        }
    }
  }
  __syncthreads();

  // ---- FC2 + bias + residual (in-place on io; col ranges disjoint per wave) ----
  f4vec acc2[2][2];
#pragma unroll
  for (int mi = 0; mi < 2; ++mi)
#pragma unroll
    for (int nj = 0; nj < 2; ++nj) acc2[mi][nj] = fz;
#pragma unroll
  for (int kk = 0; kk < 16; ++kk) {
    s8vec a0[2];
#pragma unroll
    for (int mi = 0; mi < 2; ++mi)
      a0[mi] = *(const s8vec*)(hs + (mi * 16 + li) * 512 + (((kk * 4 + g) ^ sl) << 3));
#pragma unroll
    for (int nj = 0; nj < 2; ++nj) {
      s8vec bw = *(const s8vec*)(w2 + (size_t)(w * 32 + nj * 16 + li) * 512 + kk * 32 + g * 8);
#pragma unroll
      for (int mi = 0; mi < 2; ++mi) acc2[mi][nj] = MFMA(a0[mi], bw, acc2[mi][nj]);
    }
  }
#pragma unroll
  for (int nj = 0; nj < 2; ++nj) {
    const int col = w * 32 + nj * 16 + li;
    const float bias = fc2b[col];
#pragma unroll
    for (int mi = 0; mi < 2; ++mi)
#pragma unroll
      for (int r = 0; r < 4; ++r) {
        int i = mi * 16 + g * 4 + r;
        size_t dst = (rbase + i) * 128 + col;
        io[dst] = io[dst] + acc2[mi][nj][r] + bias;
      }
  }
}

// ---------- launch ----------
extern "C" void kernel_launch(void* const* d_in, const int* in_sizes, int n_in,
                              void* d_out, int out_size, void* d_ws, size_t ws_size,
                              hipStream_t stream) {
  const float* x     = (const float*)d_in[0];
  const float* ln1w  = (const float*)d_in[1];
  const float* ln1b  = (const float*)d_in[2];
  const float* qkvw  = (const float*)d_in[3];
  const float* qkvb  = (const float*)d_in[4];
  const float* projw = (const float*)d_in[5];
  const float* projb = (const float*)d_in[6];
  const float* ln2w  = (const float*)d_in[7];
  const float* ln2b  = (const float*)d_in[8];
  const float* fc1w  = (const float*)d_in[9];
  const float* fc1b  = (const float*)d_in[10];
  const float* fc2w  = (const float*)d_in[11];
  const float* fc2b  = (const float*)d_in[12];

  short* wb = (short*)d_ws;  // bf16 weights: qkv@0, proj@49152, fc1@65536, fc2@131072
  float* out = (float*)d_out;

  wconv_k<<<768, 256, 0, stream>>>(qkvw, projw, fc1w, fc2w, wb);
  msa_k<<<2048, 256, 0, stream>>>(x, ln1w, ln1b, wb, qkvb, wb + 49152, projb, out);
  mlp_k<<<4096, 256, 0, stream>>>(ln2w, ln2b, wb + 65536, fc1b, wb + 131072, fc2b, out);
}